// Round 2
// baseline (543.874 us; speedup 1.0000x reference)
//
#include <hip/hip_runtime.h>
#include <stdint.h>

typedef __bf16 bf16_t;
typedef __bf16 bf16x8 __attribute__((ext_vector_type(8)));
typedef __bf16 bf16x4 __attribute__((ext_vector_type(4)));
typedef float  f32x16 __attribute__((ext_vector_type(16)));
typedef float  f32x4  __attribute__((ext_vector_type(4)));

#define MFMA_B16(a, b, c) __builtin_amdgcn_mfma_f32_32x32x16_bf16((a), (b), (c), 0, 0, 0)

static constexpr int kB = 65536, kDIN = 256, kG = 4, kW = 128, kD = 4, kL = 3, kH = 512;
static constexpr int kW0T = kG * kDIN * kW;           // 131072 elements
static constexpr int kWgT = kL * kG * kD * kW * kW;   // 786432 elements

// ---------------------------------------------------------------------------
// Prep: read f32 weights, convert to bf16, reorder into transposed
// fragment-linear layout for v_mfma_f32_32x32x16_bf16 A-operand reads
// (A[n][k], lane: n=l&31, k=(l>>5)*8+j). Fragment f covers a 32(n) x 16(k)
// tile, stored as 64 lanes x 16B.
//   w0t: [g][f = kt*4+nt][lane][j]   kt in 0..15 (K=256), nt in 0..3
//   wgt: [g][s = l*4+d][f = kt*4+nt][lane][j]   kt in 0..7 (K=128)
// ---------------------------------------------------------------------------
__global__ __launch_bounds__(256) void prep_weights(
    const float* __restrict__ W0, const float* __restrict__ Wg,
    bf16_t* __restrict__ w0t, bf16_t* __restrict__ wgt)
{
  int e = blockIdx.x * 256 + threadIdx.x;
  if (e < kW0T) {
    int g  = e >> 15;            // 32768 elements per group
    int r  = e & 32767;
    int f  = r >> 9;             // 64 fragments of 512 elements
    int ln = (r >> 3) & 63;
    int j  = r & 7;
    int kt = f >> 2, nt = f & 3;
    int n  = nt * 32 + (ln & 31);
    int k  = kt * 16 + ((ln >> 5) << 3) + j;
    w0t[e] = (bf16_t)W0[k * kH + g * kW + n];
  } else if (e < kW0T + kWgT) {
    int e2 = e - kW0T;
    int g  = e2 / (12 * 16384);
    int r2 = e2 - g * (12 * 16384);
    int s  = r2 >> 14;           // l*4 + d
    int r  = r2 & 16383;
    int f  = r >> 9;             // 32 fragments
    int ln = (r >> 3) & 63;
    int j  = r & 7;
    int kt = f >> 2, nt = f & 3;
    int n  = nt * 32 + (ln & 31);
    int k  = kt * 16 + ((ln >> 5) << 3) + j;
    int l  = s >> 2, d = s & 3;
    wgt[e2] = (bf16_t)Wg[((((l * kG + g) * kD + d) * kW) + k) * kW + n];
  }
}

// ---------------------------------------------------------------------------
// Fused network. Block = 128 rows x one group (128 cols). 4 waves, each wave
// owns a 64(n) x 64(m) quadrant as 2x2 tiles of 32x32 MFMA.
// Computes transposed: Yt[n][m] = sum_k W[k][n] * H[m][k]  (A=Wt frag, B=H frag)
// C/D layout: m = lane&31 (col), n = (reg&3) + 8*(reg>>2) + 4*(lane>>5) (row).
// H lives in LDS (bf16) in the same fragment-linear layout the B-operand reads:
//   frag f = kt*4 + (m>>5), lane = (m&31) + 32*((k>>3)&1), j = k&7.
// Epilogue: each lane's 4 consecutive regs are 4 consecutive k -> one b64 write.
// I/O is f32: x loaded as two dwordx4/lane and packed to bf16x8; out stored f32x4.
// ---------------------------------------------------------------------------
__global__ __launch_bounds__(256, 2) void resnext_fused(
    const float* __restrict__ x, const float* __restrict__ b0,
    const float* __restrict__ bg, const bf16_t* __restrict__ w0t,
    const bf16_t* __restrict__ wgt, float* __restrict__ out)
{
  __shared__ bf16_t sH[16384];   // 32 KB h tile (128m x 128k), frag-linear
  __shared__ bf16_t sW[16384];   // 32 KB weight tile, frag-linear

  const int tid = threadIdx.x;
  const int ln  = tid & 63;
  const int wv  = tid >> 6;
  const int rr  = wv >> 1;       // m-half (rows)
  const int cc  = wv & 1;        // n-half (cols)
  const int l31 = ln & 31;
  const int l5  = ln >> 5;

  const int g  = blockIdx.x & 3;
  const int r0 = (blockIdx.x >> 2) << 7;

  const bf16_t* wgt_g = wgt + g * (12 * 16384);

  // prefetch chain weight 0 into registers (staged to LDS at initial epilogue)
  int4 pw[8];
  #pragma unroll
  for (int jj = 0; jj < 8; ++jj)
    pw[jj] = *(const int4*)(wgt_g + (jj * 256 + tid) * 8);

  f32x16 acc[2][2];
  #pragma unroll
  for (int a = 0; a < 2; ++a)
    #pragma unroll
    for (int b = 0; b < 2; ++b)
      #pragma unroll
      for (int q = 0; q < 16; ++q) acc[a][b][q] = 0.f;

  // ---------- initial GEMM: x0t[n][m], K=256; A frags from ws, B from x (f32->bf16)
  {
    const bf16_t* w0t_g = w0t + g * 32768;
    const float* xb = x + (size_t)(r0 + rr * 64 + l31) * kDIN + l5 * 8;
    #pragma unroll
    for (int kt = 0; kt < 16; ++kt) {
      bf16x8 a0 = *(const bf16x8*)(w0t_g + (kt * 4 + cc * 2 + 0) * 512 + ln * 8);
      bf16x8 a1 = *(const bf16x8*)(w0t_g + (kt * 4 + cc * 2 + 1) * 512 + ln * 8);
      bf16x8 h[2];
      #pragma unroll
      for (int mt = 0; mt < 2; ++mt) {
        f32x4 f0 = *(const f32x4*)(xb + mt * 32 * kDIN + kt * 16);
        f32x4 f1 = *(const f32x4*)(xb + mt * 32 * kDIN + kt * 16 + 4);
        #pragma unroll
        for (int q = 0; q < 4; ++q) {
          h[mt][q]     = (bf16_t)f0[q];
          h[mt][q + 4] = (bf16_t)f1[q];
        }
      }
      acc[0][0] = MFMA_B16(a0, h[0], acc[0][0]);
      acc[0][1] = MFMA_B16(a0, h[1], acc[0][1]);
      acc[1][0] = MFMA_B16(a1, h[0], acc[1][0]);
      acc[1][1] = MFMA_B16(a1, h[1], acc[1][1]);
    }
  }

  bf16x4 x0v[2][2][4], residv[2][2][4];

  // ---------- initial epilogue: relu(x@W0+b0) -> x0 regs + LDS; stage weight 0
  {
    const float* b0g = b0 + g * kW;
    #pragma unroll
    for (int nt2 = 0; nt2 < 2; ++nt2) {
      #pragma unroll
      for (int gi = 0; gi < 4; ++gi) {
        f32x4 bv = *(const f32x4*)(b0g + cc * 64 + nt2 * 32 + gi * 8 + l5 * 4);
        #pragma unroll
        for (int mt2 = 0; mt2 < 2; ++mt2) {
          bf16x4 o;
          #pragma unroll
          for (int r = 0; r < 4; ++r) {
            float v = acc[nt2][mt2][gi * 4 + r] + bv[r];
            v = fmaxf(v, 0.f);
            o[r] = (bf16_t)v;
          }
          x0v[nt2][mt2][gi] = o;
          residv[nt2][mt2][gi] = o;
          const int kt   = cc * 4 + nt2 * 2 + (gi >> 1);
          const int mt32 = rr * 2 + mt2;
          *(bf16x4*)(sH + (kt * 4 + mt32) * 512 + (l31 + 32 * (gi & 1)) * 8 + l5 * 4) = o;
        }
      }
    }
    #pragma unroll
    for (int jj = 0; jj < 8; ++jj)
      *(int4*)(sW + (jj * 256 + tid) * 8) = pw[jj];
  }
  __syncthreads();

  // ---------- chain steps 1..11 (LDS round-trip); step 12 peeled below
  #pragma unroll 1
  for (int s = 1; s <= 11; ++s) {
    const int  lidx      = (s - 1) >> 2;
    const int  d         = (s - 1) & 3;
    const bool layer_end = (d == 3);

    // prefetch next step's weight (hidden under MFMA)
    #pragma unroll
    for (int jj = 0; jj < 8; ++jj)
      pw[jj] = *(const int4*)(wgt_g + s * 16384 + (jj * 256 + tid) * 8);

    #pragma unroll
    for (int a = 0; a < 2; ++a)
      #pragma unroll
      for (int b = 0; b < 2; ++b)
        #pragma unroll
        for (int q = 0; q < 16; ++q) acc[a][b][q] = 0.f;

    #pragma unroll
    for (int kt = 0; kt < 8; ++kt) {
      bf16x8 a0 = *(const bf16x8*)(sW + (kt * 4 + cc * 2 + 0) * 512 + ln * 8);
      bf16x8 a1 = *(const bf16x8*)(sW + (kt * 4 + cc * 2 + 1) * 512 + ln * 8);
      bf16x8 h0 = *(const bf16x8*)(sH + (kt * 4 + rr * 2 + 0) * 512 + ln * 8);
      bf16x8 h1 = *(const bf16x8*)(sH + (kt * 4 + rr * 2 + 1) * 512 + ln * 8);
      acc[0][0] = MFMA_B16(a0, h0, acc[0][0]);
      acc[0][1] = MFMA_B16(a0, h1, acc[0][1]);
      acc[1][0] = MFMA_B16(a1, h0, acc[1][0]);
      acc[1][1] = MFMA_B16(a1, h1, acc[1][1]);
    }

    __syncthreads();   // all waves done reading sH/sW

    const float* bptr = bg + ((lidx * kG + g) * kD + d) * kW;
    #pragma unroll
    for (int nt2 = 0; nt2 < 2; ++nt2) {
      #pragma unroll
      for (int gi = 0; gi < 4; ++gi) {
        f32x4 bv = *(const f32x4*)(bptr + cc * 64 + nt2 * 32 + gi * 8 + l5 * 4);
        #pragma unroll
        for (int mt2 = 0; mt2 < 2; ++mt2) {
          bf16x4 o;
          #pragma unroll
          for (int r = 0; r < 4; ++r) {
            float v = acc[nt2][mt2][gi * 4 + r] + bv[r];
            v = fmaxf(v, 0.f);
            if (layer_end) {
              v += (float)residv[nt2][mt2][gi][r];
              v = fmaxf(v, 0.f);
            }
            o[r] = (bf16_t)v;
          }
          if (layer_end) residv[nt2][mt2][gi] = o;
          const int kt   = cc * 4 + nt2 * 2 + (gi >> 1);
          const int mt32 = rr * 2 + mt2;
          *(bf16x4*)(sH + (kt * 4 + mt32) * 512 + (l31 + 32 * (gi & 1)) * 8 + l5 * 4) = o;
        }
      }
    }
    #pragma unroll
    for (int jj = 0; jj < 8; ++jj)
      *(int4*)(sW + (jj * 256 + tid) * 8) = pw[jj];
    __syncthreads();
  }

  // ---------- step 12 (l=2,d=3): bias+relu, +resid relu, +x0 relu, store f32 out
  {
    #pragma unroll
    for (int a = 0; a < 2; ++a)
      #pragma unroll
      for (int b = 0; b < 2; ++b)
        #pragma unroll
        for (int q = 0; q < 16; ++q) acc[a][b][q] = 0.f;

    #pragma unroll
    for (int kt = 0; kt < 8; ++kt) {
      bf16x8 a0 = *(const bf16x8*)(sW + (kt * 4 + cc * 2 + 0) * 512 + ln * 8);
      bf16x8 a1 = *(const bf16x8*)(sW + (kt * 4 + cc * 2 + 1) * 512 + ln * 8);
      bf16x8 h0 = *(const bf16x8*)(sH + (kt * 4 + rr * 2 + 0) * 512 + ln * 8);
      bf16x8 h1 = *(const bf16x8*)(sH + (kt * 4 + rr * 2 + 1) * 512 + ln * 8);
      acc[0][0] = MFMA_B16(a0, h0, acc[0][0]);
      acc[0][1] = MFMA_B16(a0, h1, acc[0][1]);
      acc[1][0] = MFMA_B16(a1, h0, acc[1][0]);
      acc[1][1] = MFMA_B16(a1, h1, acc[1][1]);
    }

    const float* bptr = bg + ((2 * kG + g) * kD + 3) * kW;
    #pragma unroll
    for (int nt2 = 0; nt2 < 2; ++nt2) {
      #pragma unroll
      for (int gi = 0; gi < 4; ++gi) {
        f32x4 bv = *(const f32x4*)(bptr + cc * 64 + nt2 * 32 + gi * 8 + l5 * 4);
        #pragma unroll
        for (int mt2 = 0; mt2 < 2; ++mt2) {
          f32x4 o;
          #pragma unroll
          for (int r = 0; r < 4; ++r) {
            float v = acc[nt2][mt2][gi * 4 + r] + bv[r];
            v = fmaxf(v, 0.f);                       // relu(h Wg + bg)
            v += (float)residv[nt2][mt2][gi][r];
            v = fmaxf(v, 0.f);                       // relu(branch + resid)
            v += (float)x0v[nt2][mt2][gi][r];
            v = fmaxf(v, 0.f);                       // relu(h + x0)
            o[r] = v;
          }
          const int row = r0 + rr * 64 + mt2 * 32 + l31;
          const int col = g * kW + cc * 64 + nt2 * 32 + gi * 8 + l5 * 4;
          *(f32x4*)(out + (size_t)row * kH + col) = o;
        }
      }
    }
  }
}

extern "C" void kernel_launch(void* const* d_in, const int* in_sizes, int n_in,
                              void* d_out, int out_size, void* d_ws, size_t ws_size,
                              hipStream_t stream) {
  const float* x  = (const float*)d_in[0];
  const float* W0 = (const float*)d_in[1];
  const float* b0 = (const float*)d_in[2];
  const float* Wg = (const float*)d_in[3];
  const float* bg = (const float*)d_in[4];
  float* outp = (float*)d_out;

  bf16_t* w0t = (bf16_t*)d_ws;          // 131072 elems bf16
  bf16_t* wgt = w0t + kW0T;             // 786432 elems bf16 (1.75 MB of ws total)

  const int prep_total = kW0T + kWgT;   // 917504
  prep_weights<<<(prep_total + 255) / 256, 256, 0, stream>>>(W0, Wg, w0t, wgt);

  const int grid = (kB / 128) * kG;     // 2048 blocks
  resnext_fused<<<grid, 256, 0, stream>>>(x, b0, bg, w0t, wgt, outp);
}

// Round 3
// 459.135 us; speedup vs baseline: 1.1846x; 1.1846x over previous
//
#include <hip/hip_runtime.h>
#include <stdint.h>

typedef __bf16 bf16_t;
typedef __bf16 bf16x8 __attribute__((ext_vector_type(8)));
typedef __bf16 bf16x4 __attribute__((ext_vector_type(4)));
typedef float  f32x16 __attribute__((ext_vector_type(16)));
typedef float  f32x4  __attribute__((ext_vector_type(4)));

#define MFMA_B16(a, b, c) __builtin_amdgcn_mfma_f32_32x32x16_bf16((a), (b), (c), 0, 0, 0)

static constexpr int kG = 4, kD = 4, kH = 512;
static constexpr int kW0T = 4 * 256 * 128;            // 131072 elements
static constexpr int kWgT = 3 * 4 * 4 * 128 * 128;    // 786432 elements

// sigma: within a 32-wide n-tile, position n=[gi1 gi0 h r1 r0] -> logical unit
// u=[gi0 h gi1 r1 r0]. With weight columns stored permuted by sigma, the MFMA
// C/D quads of one step are directly the B-operand fragments of the next step.
__device__ __host__ inline int sigma_tile(int n) {
  int gi = n >> 3, h = (n >> 2) & 1, r = n & 3;
  return 16 * (gi & 1) + 8 * h + 4 * (gi >> 1) + r;
}

// ---------------------------------------------------------------------------
// Prep: f32 weights -> bf16 frag-linear, columns permuted by sigma.
//   w0t: [g][f = kt*4+nt][ln][j]  kt 0..15 (K=256 DIN, identity on k)
//   wgt: [g][m = l*4+d][f = kt*4+nt][ln][j]  kt 0..7 (K=128, u-space identity)
// ---------------------------------------------------------------------------
__global__ __launch_bounds__(256) void prep_weights(
    const float* __restrict__ W0, const float* __restrict__ Wg,
    bf16_t* __restrict__ w0t, bf16_t* __restrict__ wgt)
{
  int e = blockIdx.x * 256 + threadIdx.x;
  if (e < kW0T) {
    int g  = e >> 15;
    int r  = e & 32767;
    int f  = r >> 9;
    int ln = (r >> 3) & 63;
    int j  = r & 7;
    int kt = f >> 2, nt = f & 3;
    int col = nt * 32 + sigma_tile(ln & 31);
    int k   = kt * 16 + ((ln >> 5) << 3) + j;
    w0t[e] = (bf16_t)W0[k * kH + g * 128 + col];
  } else if (e < kW0T + kWgT) {
    int e2 = e - kW0T;
    int g  = e2 / (12 * 16384);
    int r2 = e2 - g * (12 * 16384);
    int m  = r2 >> 14;           // l*4 + d
    int r  = r2 & 16383;
    int f  = r >> 9;
    int ln = (r >> 3) & 63;
    int j  = r & 7;
    int kt = f >> 2, nt = f & 3;
    int col = nt * 32 + sigma_tile(ln & 31);
    int k   = kt * 16 + ((ln >> 5) << 3) + j;
    int l   = m >> 2, d = m & 3;
    wgt[e2] = (bf16_t)Wg[((((l * kG + g) * kD + d) * 128) + k) * 128 + col];
  }
}

// ---------------------------------------------------------------------------
// Fused network, register-resident h. Block = 128 rows x one group; 4 waves,
// wave w owns rows r0+32w..+31 (lane row = base + (ln&31)) and full n=0..127.
// acc[t] (t = n-tile) f32x16; C quad (t,gi) holds logical unit
// u = 32t+16(gi&1)+8l5+4(gi>>1)+r, so frag(kt) = [quad(kt>>1, kt&1),
// quad(kt>>1, 2+(kt&1))] -- pure register aliasing (keepA/keepB).
// Weights: 2x32KB LDS double buffer via global_load_lds(16B), 1 barrier/step.
// Final store via XOR-swizzled LDS f32 transpose -> full-line coalesced writes.
// ---------------------------------------------------------------------------
__global__ __launch_bounds__(256, 2) void resnext_fused(
    const float* __restrict__ x, const float* __restrict__ b0,
    const float* __restrict__ bg, const bf16_t* __restrict__ w0t,
    const bf16_t* __restrict__ wgt, float* __restrict__ out)
{
  __shared__ bf16_t sW[2][16384];     // 64 KB: weight dbuf; reused as f32 tile
  __shared__ float  sBias[13 * 128];  // slot 0 = b0, slots 1..12 = bg steps

  const int tid = threadIdx.x;
  const int ln  = tid & 63;
  const int wv  = tid >> 6;
  const int l31 = ln & 31;
  const int l5  = ln >> 5;

  const int g  = blockIdx.x >> 9;          // g-major: x streams once
  const int r0 = (blockIdx.x & 511) << 7;

  const bf16_t* wgt_g = wgt + g * (12 * 16384);

  // stage biases (b0 slice + 12 bg slices)
  for (int i = tid; i < 13 * 128; i += 256) {
    float v;
    if (i < 128) v = b0[g * 128 + i];
    else {
      int m = (i - 128) >> 7, u = (i - 128) & 127;
      int l = m >> 2, d = m & 3;
      v = bg[((l * kG + g) * kD + d) * 128 + u];
    }
    sBias[i] = v;
  }

  // async stage of chain step m -> buf (8 frags/wave, 1KB each, lane*16B dest)
  auto stage = [&](int m, int buf) {
    #pragma unroll
    for (int i = 0; i < 8; ++i) {
      int frag = wv * 8 + i;
      __builtin_amdgcn_global_load_lds(
          (const __attribute__((address_space(1))) void*)(wgt_g + m * 16384 + frag * 512 + ln * 8),
          (__attribute__((address_space(3))) void*)(&sW[buf][frag * 512]),
          16, 0, 0);
    }
  };

  stage(0, 0);   // step-0 weights in flight under the initial GEMM

  f32x16 acc[4];
  #pragma unroll
  for (int t = 0; t < 4; ++t)
    #pragma unroll
    for (int q = 0; q < 16; ++q) acc[t][q] = 0.f;

  // ---------- initial GEMM: K=256, A (W0t) from global/L2, B from x
  {
    const bf16_t* w0g = w0t + g * 32768;
    const float* xb = x + (size_t)(r0 + wv * 32 + l31) * 256 + l5 * 8;
    #pragma unroll
    for (int kt = 0; kt < 16; ++kt) {
      f32x4 xa = *(const f32x4*)(xb + kt * 16);
      f32x4 xc = *(const f32x4*)(xb + kt * 16 + 4);
      bf16x8 bfr;
      #pragma unroll
      for (int q = 0; q < 4; ++q) {
        bfr[q]     = (bf16_t)xa[q];
        bfr[q + 4] = (bf16_t)xc[q];
      }
      #pragma unroll
      for (int nt = 0; nt < 4; ++nt) {
        bf16x8 a = *(const bf16x8*)(w0g + (kt * 4 + nt) * 512 + ln * 8);
        acc[nt] = MFMA_B16(a, bfr, acc[nt]);
      }
    }
  }
  __syncthreads();   // sBias + step-0 weights landed

  bf16x8 keepA[4], keepB[4], x0A[4], x0B[4], resA[4], resB[4];

  // ---------- initial epilogue: relu(x@W0 + b0) -> keep/x0/resid registers
  #pragma unroll
  for (int t = 0; t < 4; ++t) {
    #pragma unroll
    for (int gi = 0; gi < 4; ++gi) {
      f32x4 bv = *(const f32x4*)(sBias + 32 * t + 16 * (gi & 1) + 8 * l5 + 4 * (gi >> 1));
      #pragma unroll
      for (int r = 0; r < 4; ++r) {
        float v = acc[t][gi * 4 + r] + bv[r];
        v = fmaxf(v, 0.f);
        bf16_t o = (bf16_t)v;
        int half = (gi >> 1) * 4 + r;
        if (gi & 1) keepB[t][half] = o; else keepA[t][half] = o;
      }
    }
    x0A[t] = keepA[t]; x0B[t] = keepB[t];
    resA[t] = keepA[t]; resB[t] = keepB[t];
  }

  // ---------- chain steps m = 0..11, one barrier per step
  #pragma unroll 1
  for (int m = 0; m < 12; ++m) {
    if (m < 11) stage(m + 1, (m + 1) & 1);

    const bf16_t* wb = sW[m & 1];
    #pragma unroll
    for (int t = 0; t < 4; ++t)
      #pragma unroll
      for (int q = 0; q < 16; ++q) acc[t][q] = 0.f;

    #pragma unroll
    for (int kt = 0; kt < 8; ++kt) {
      bf16x8 bfr = (kt & 1) ? keepB[kt >> 1] : keepA[kt >> 1];
      #pragma unroll
      for (int nt = 0; nt < 4; ++nt) {
        bf16x8 a = *(const bf16x8*)(wb + (kt * 4 + nt) * 512 + ln * 8);
        acc[nt] = MFMA_B16(a, bfr, acc[nt]);
      }
    }

    const bool layer_end = ((m & 3) == 3);
    const float* bptr = sBias + (m + 1) * 128;

    if (m < 11) {
      #pragma unroll
      for (int t = 0; t < 4; ++t) {
        #pragma unroll
        for (int gi = 0; gi < 4; ++gi) {
          f32x4 bv = *(const f32x4*)(bptr + 32 * t + 16 * (gi & 1) + 8 * l5 + 4 * (gi >> 1));
          #pragma unroll
          for (int r = 0; r < 4; ++r) {
            float v = acc[t][gi * 4 + r] + bv[r];
            v = fmaxf(v, 0.f);
            if (layer_end) {
              bf16x8 src = (gi & 1) ? resB[t] : resA[t];
              v += (float)src[(gi >> 1) * 4 + r];
              v = fmaxf(v, 0.f);
            }
            bf16_t o = (bf16_t)v;
            int half = (gi >> 1) * 4 + r;
            if (gi & 1) keepB[t][half] = o; else keepA[t][half] = o;
          }
        }
        if (layer_end) { resA[t] = keepA[t]; resB[t] = keepB[t]; }
      }
      __syncthreads();   // step-m reads done; step-(m+1) weights landed
    } else {
      // final step: bias+relu, +resid relu, +x0 relu -> f32, via LDS transpose
      float fin[4][16];
      #pragma unroll
      for (int t = 0; t < 4; ++t) {
        #pragma unroll
        for (int gi = 0; gi < 4; ++gi) {
          f32x4 bv = *(const f32x4*)(bptr + 32 * t + 16 * (gi & 1) + 8 * l5 + 4 * (gi >> 1));
          #pragma unroll
          for (int r = 0; r < 4; ++r) {
            float v = acc[t][gi * 4 + r] + bv[r];
            v = fmaxf(v, 0.f);
            bf16x8 rs = (gi & 1) ? resB[t] : resA[t];
            v += (float)rs[(gi >> 1) * 4 + r];
            v = fmaxf(v, 0.f);
            bf16x8 xs = (gi & 1) ? x0B[t] : x0A[t];
            v += (float)xs[(gi >> 1) * 4 + r];
            v = fmaxf(v, 0.f);
            fin[t][gi * 4 + r] = v;
          }
        }
      }
      __syncthreads();   // everyone done reading sW before tile overwrite

      float* sT = (float*)sW;   // 128 x 128 f32 tile, XOR-swizzled columns
      const int row = wv * 32 + l31;
      #pragma unroll
      for (int t = 0; t < 4; ++t) {
        #pragma unroll
        for (int gi = 0; gi < 4; ++gi) {
          int u = 32 * t + 16 * (gi & 1) + 8 * l5 + 4 * (gi >> 1);
          int col_s = u ^ ((l31 & 7) << 2);
          f32x4 v;
          #pragma unroll
          for (int r = 0; r < 4; ++r) v[r] = fin[t][gi * 4 + r];
          *(f32x4*)(sT + row * 128 + col_s) = v;
        }
      }
      __syncthreads();

      #pragma unroll
      for (int it = 0; it < 16; ++it) {
        int chunk = it * 256 + tid;
        int rw = chunk >> 5, c = chunk & 31;
        int col_s = (4 * c) ^ ((rw & 7) << 2);
        f32x4 v = *(const f32x4*)(sT + rw * 128 + col_s);
        *(f32x4*)(out + (size_t)(r0 + rw) * kH + g * 128 + 4 * c) = v;
      }
    }
  }
}

extern "C" void kernel_launch(void* const* d_in, const int* in_sizes, int n_in,
                              void* d_out, int out_size, void* d_ws, size_t ws_size,
                              hipStream_t stream) {
  const float* x  = (const float*)d_in[0];
  const float* W0 = (const float*)d_in[1];
  const float* b0 = (const float*)d_in[2];
  const float* Wg = (const float*)d_in[3];
  const float* bg = (const float*)d_in[4];
  float* outp = (float*)d_out;

  bf16_t* w0t = (bf16_t*)d_ws;
  bf16_t* wgt = w0t + kW0T;

  const int prep_total = kW0T + kWgT;
  prep_weights<<<(prep_total + 255) / 256, 256, 0, stream>>>(W0, Wg, w0t, wgt);

  resnext_fused<<<2048, 256, 0, stream>>>(x, b0, bg, w0t, wgt, outp);
}